// Round 3
// baseline (298.868 us; speedup 1.0000x reference)
//
#include <hip/hip_runtime.h>
#include <hip/hip_bf16.h>

// Problem constants: B=8, C=192, H=W=128, NH=6, HD=32, N=16384
constexpr int B   = 8;
constexpr int Cc  = 192;
constexpr int H   = 128;
constexpr int Wd  = 128;
constexpr int NH  = 6;
constexpr int HW  = H * Wd;       // 16384
constexpr int QKV = 3 * Cc;       // 576

typedef short s16x4 __attribute__((ext_vector_type(4)));
typedef short s16x8 __attribute__((ext_vector_type(8)));
typedef float f32x16 __attribute__((ext_vector_type(16)));

// Workspace layout (bytes):
//   qkv  : [B][576][HW] bf16           = 150,994,944
//   attn : [B][NH][32][32] fp32        =     196,608
//   ssq  : [2][B][Cc] fp32 (q then k)  =      12,288
//   M    : [B][192][192] bf16 ([o][c]) =     589,824
constexpr size_t OFF_QKV  = 0;
constexpr size_t OFF_ATTN = 150994944ULL;
constexpr size_t OFF_SSQ  = OFF_ATTN + 196608ULL;
constexpr size_t OFF_M    = OFF_SSQ + 12288ULL;
constexpr int    N_ZERO   = (196608 + 12288) / 4;   // attn+ssq floats

__device__ inline unsigned short f2bf(float f) {
    __hip_bfloat16 h = __float2bfloat16(f);
    return *(unsigned short*)&h;
}

__global__ void zero_kernel(float* __restrict__ p, int n) {
    int i = blockIdx.x * 256 + threadIdx.x;
    if (i < n) p[i] = 0.f;
}

// ---------------------------------------------------------------------------
// K1: grouped 3x3 conv, groups=C, out=3C bf16. o = 3*g + j uses input ch g.
// LDS-free: each thread computes 8 consecutive x in one row for 3 output
// channels from a 3x10 register window (global loads; halos via L1).
// grid: (8 row-tiles, 192 groups, 8 batch), block 256 = 16 rows x 16 threads.
// ---------------------------------------------------------------------------
constexpr int TS = 16;

__global__ __launch_bounds__(256) void conv_qkv(
    const float* __restrict__ x, const float* __restrict__ w,
    const float* __restrict__ bias, unsigned short* __restrict__ qkv,
    float* __restrict__ ssq)
{
    int tile = blockIdx.x;
    int g    = blockIdx.y;
    int b    = blockIdx.z;
    int tid  = threadIdx.x;
    int y    = tile * TS + (tid >> 4);
    int xq   = (tid & 15) * 8;

    const float* xp = x + ((size_t)b * Cc + g) * HW;

    float r[3][10];
    for (int dr = 0; dr < 3; ++dr) {
        int yy = y - 1 + dr;
        bool vy = (yy >= 0) && (yy < H);
        const float* rp = xp + (size_t)yy * Wd;
        if (vy) {
            float4 a4 = *(const float4*)(rp + xq);
            float4 b4 = *(const float4*)(rp + xq + 4);
            r[dr][0] = (xq > 0)   ? rp[xq - 1] : 0.f;
            r[dr][1] = a4.x; r[dr][2] = a4.y; r[dr][3] = a4.z; r[dr][4] = a4.w;
            r[dr][5] = b4.x; r[dr][6] = b4.y; r[dr][7] = b4.z; r[dr][8] = b4.w;
            r[dr][9] = (xq < 120) ? rp[xq + 8] : 0.f;
        } else {
            for (int i = 0; i < 10; ++i) r[dr][i] = 0.f;
        }
    }

    float wreg[3][9], breg[3];
    for (int j = 0; j < 3; ++j) {
        const float* wp = w + (size_t)(3 * g + j) * 9;
        for (int t = 0; t < 9; ++t) wreg[j][t] = wp[t];
        breg[j] = bias[3 * g + j];
    }

    bool track = (g < 128);
    float ss[3] = {0.f, 0.f, 0.f};

    for (int j = 0; j < 3; ++j) {
        unsigned short pk[8];
        for (int xx = 0; xx < 8; ++xx) {
            float s = breg[j];
            for (int dr = 0; dr < 3; ++dr)
                s += wreg[j][dr * 3 + 0] * r[dr][xx]
                   + wreg[j][dr * 3 + 1] * r[dr][xx + 1]
                   + wreg[j][dr * 3 + 2] * r[dr][xx + 2];
            if (track) ss[j] += s * s;
            pk[xx] = f2bf(s);
        }
        unsigned short* op = qkv + ((size_t)b * QKV + 3 * g + j) * HW
                                 + (size_t)y * Wd + xq;
        uint4 uu;
        uu.x = (unsigned int)pk[0] | ((unsigned int)pk[1] << 16);
        uu.y = (unsigned int)pk[2] | ((unsigned int)pk[3] << 16);
        uu.z = (unsigned int)pk[4] | ((unsigned int)pk[5] << 16);
        uu.w = (unsigned int)pk[6] | ((unsigned int)pk[7] << 16);
        *(uint4*)op = uu;
    }

    if (track) {
        __shared__ float red[256];
        for (int j = 0; j < 3; ++j) {
            red[tid] = ss[j];
            __syncthreads();
            for (int st = 128; st > 0; st >>= 1) {
                if (tid < st) red[tid] += red[tid + st];
                __syncthreads();
            }
            if (tid == 0) {
                int o = 3 * g + j;
                atomicAdd(&ssq[(o < Cc ? 0 : 1) * B * Cc + b * Cc + (o % Cc)], red[0]);
            }
            __syncthreads();
        }
    }
}

// ---------------------------------------------------------------------------
// K2: attn[b,h] += q @ k^T via MFMA 32x32x16, fragments straight from global
// (both operands are n-contiguous). 4 waves per block on distinct n-segments;
// non-atomic LDS stores + tree reduce, then one global atomicAdd per element.
// grid: (16, NH, B), block 256.
// ---------------------------------------------------------------------------
constexpr int NSEG = 64;
constexpr int SEGN = HW / NSEG;   // 256

__global__ __launch_bounds__(256) void qk_mfma(
    const unsigned short* __restrict__ qkv, float* __restrict__ attn)
{
    int h = blockIdx.y, b = blockIdx.z;
    int tid = threadIdx.x;
    int wv = tid >> 6, lane = tid & 63;
    int seg = blockIdx.x * 4 + wv;
    int col = lane & 31, half = lane >> 5;

    __shared__ float sred[4][1024];

    const unsigned short* qp = qkv + ((size_t)b * QKV + h * 32 + col) * HW
                                   + seg * SEGN + half * 8;
    const unsigned short* kp = qp + (size_t)Cc * HW;

    f32x16 acc0, acc1;
    for (int i = 0; i < 16; ++i) { acc0[i] = 0.f; acc1[i] = 0.f; }

    for (int kk = 0; kk < SEGN; kk += 32) {
        s16x8 a0 = *(const s16x8*)(qp + kk);
        s16x8 b0 = *(const s16x8*)(kp + kk);
        acc0 = __builtin_amdgcn_mfma_f32_32x32x16_bf16(a0, b0, acc0, 0, 0, 0);
        s16x8 a1 = *(const s16x8*)(qp + kk + 16);
        s16x8 b1 = *(const s16x8*)(kp + kk + 16);
        acc1 = __builtin_amdgcn_mfma_f32_32x32x16_bf16(a1, b1, acc1, 0, 0, 0);
    }

    int rb = half * 4;
    for (int r = 0; r < 16; ++r) {
        int row = (r & 3) + 8 * (r >> 2) + rb;
        sred[wv][row * 32 + col] = acc0[r] + acc1[r];
    }
    __syncthreads();
    float* ap = attn + (size_t)(b * NH + h) * 1024;
    for (int i = tid; i < 1024; i += 256)
        atomicAdd(&ap[i], sred[0][i] + sred[1][i] + sred[2][i] + sred[3][i]);
}

// ---------------------------------------------------------------------------
// K2b: scale by 1/(||q_c|| ||k_d||) * temperature[h], softmax over d.
// ---------------------------------------------------------------------------
__global__ void softmax_attn(float* __restrict__ attn,
                             const float* __restrict__ ssq,
                             const float* __restrict__ temp)
{
    int h = blockIdx.x % NH, b = blockIdx.x / NH;
    __shared__ float nk[32];
    if (threadIdx.x < 32)
        nk[threadIdx.x] = fmaxf(sqrtf(ssq[B * Cc + b * Cc + h * 32 + threadIdx.x]), 1e-12f);
    __syncthreads();
    int c = threadIdx.x;
    if (c >= 32) return;
    float nq = fmaxf(sqrtf(ssq[b * Cc + h * 32 + c]), 1e-12f);
    float t = temp[h];
    float* ap = attn + ((size_t)(b * NH + h) * 32 + c) * 32;
    float row[32];
    float mx = -1e30f;
    for (int d = 0; d < 32; ++d) {
        float v = ap[d] / (nq * nk[d]) * t;
        row[d] = v;
        mx = fmaxf(mx, v);
    }
    float sum = 0.f;
    for (int d = 0; d < 32; ++d) { row[d] = expf(row[d] - mx); sum += row[d]; }
    float inv = 1.f / sum;
    for (int d = 0; d < 32; ++d) ap[d] = row[d] * inv;
}

// ---------------------------------------------------------------------------
// K3a: M[b][o][c=h*32+d] = sum_{c'} w_out[o][h*32+c'] * attn[b][h][c'][d], bf16.
// ---------------------------------------------------------------------------
__global__ __launch_bounds__(256) void make_m(
    const float* __restrict__ attn, const float* __restrict__ w_out,
    unsigned short* __restrict__ M)
{
    int h = blockIdx.x, b = blockIdx.y;
    __shared__ float as[32][33];
    for (int i = threadIdx.x; i < 1024; i += 256)
        as[i / 32][i % 32] = attn[(size_t)((b * NH + h) * 32 + i / 32) * 32 + i % 32];
    __syncthreads();
    for (int i = threadIdx.x; i < Cc * 32; i += 256) {
        int o = i / 32, d = i % 32;
        const float* wp = w_out + (size_t)o * Cc + h * 32;
        float s = 0.f;
        for (int cp = 0; cp < 32; ++cp) s += wp[cp] * as[cp][d];
        M[((size_t)b * Cc + o) * Cc + h * 32 + d] = f2bf(s);
    }
}

// ---------------------------------------------------------------------------
// K3b: out[b][o][n] = sum_c M[o][c] * v[c][n] + b_out[o] via MFMA 32x32x16.
// Per-wave autonomous: wave tile 192o x 32n, no __syncthreads. Each wave
// stages its own 16c x 32n v-transpose in a private LDS region.
// LDS row stride 20 shorts: write banks = 8*(lane&7) + (lane>>3) mod 32
// (conflict-free); b64 reads 2-way (free). grid: (128, 8), block 256.
// ---------------------------------------------------------------------------
constexpr int BN = 128;

__global__ __launch_bounds__(256) void out_gemm(
    const unsigned short* __restrict__ M, const unsigned short* __restrict__ qkv,
    const float* __restrict__ b_out, float* __restrict__ out)
{
    int tid  = threadIdx.x;
    int wv   = tid >> 6, lane = tid & 63;
    int b    = blockIdx.y;
    int n0   = blockIdx.x * BN + wv * 32;    // wave's 32-wide n range
    int col  = lane & 31, half = lane >> 5;
    int a    = lane >> 3;                    // c-pair 0..7
    int bq   = lane & 7;                     // n-quad 0..7

    __shared__ unsigned short vsT[4][32][20];
    unsigned short (*vt)[20] = vsT[wv];

    const unsigned short* vp = qkv + ((size_t)b * QKV + 2 * Cc) * HW + n0 + 4 * bq;
    const unsigned short* mp = M + (size_t)b * Cc * Cc;

    f32x16 acc[6];
    for (int t = 0; t < 6; ++t)
        for (int i = 0; i < 16; ++i) acc[t][i] = 0.f;

    // prefetch k0 = 0
    const unsigned short* s0 = vp + (size_t)(2 * a) * HW;
    ushort4 va = *(const ushort4*)s0;
    ushort4 vb = *(const ushort4*)(s0 + HW);

    for (int k0 = 0; k0 < Cc; k0 += 16) {
        *(unsigned int*)&vt[4 * bq + 0][2 * a] = (unsigned int)va.x | ((unsigned int)vb.x << 16);
        *(unsigned int*)&vt[4 * bq + 1][2 * a] = (unsigned int)va.y | ((unsigned int)vb.y << 16);
        *(unsigned int*)&vt[4 * bq + 2][2 * a] = (unsigned int)va.z | ((unsigned int)vb.z << 16);
        *(unsigned int*)&vt[4 * bq + 3][2 * a] = (unsigned int)va.w | ((unsigned int)vb.w << 16);
        if (k0 + 16 < Cc) {
            const unsigned short* s1 = vp + (size_t)(k0 + 16 + 2 * a) * HW;
            va = *(const ushort4*)s1;
            vb = *(const ushort4*)(s1 + HW);
        }
        __builtin_amdgcn_wave_barrier();
        s16x4 lo = *(const s16x4*)&vt[col][half * 8];
        s16x4 hi = *(const s16x4*)&vt[col][half * 8 + 4];
        s16x8 bf = __builtin_shufflevector(lo, hi, 0, 1, 2, 3, 4, 5, 6, 7);
        for (int mt = 0; mt < 6; ++mt) {
            s16x8 af = *(const s16x8*)(mp + (size_t)(mt * 32 + col) * Cc + k0 + half * 8);
            acc[mt] = __builtin_amdgcn_mfma_f32_32x32x16_bf16(af, bf, acc[mt], 0, 0, 0);
        }
        __builtin_amdgcn_wave_barrier();
    }

    for (int mt = 0; mt < 6; ++mt) {
        f32x16 c = acc[mt];
        for (int rr = 0; rr < 16; ++rr) {
            int row = (rr & 3) + 8 * (rr >> 2) + 4 * half;
            int o = mt * 32 + row;
            out[((size_t)b * Cc + o) * HW + n0 + col] = c[rr] + b_out[o];
        }
    }
}

extern "C" void kernel_launch(void* const* d_in, const int* in_sizes, int n_in,
                              void* d_out, int out_size, void* d_ws, size_t ws_size,
                              hipStream_t stream) {
    const float* x      = (const float*)d_in[0];
    const float* w_qkv  = (const float*)d_in[1];
    const float* b_qkv  = (const float*)d_in[2];
    const float* temp   = (const float*)d_in[3];
    const float* w_out  = (const float*)d_in[4];
    const float* b_out  = (const float*)d_in[5];
    float* out = (float*)d_out;

    char* ws = (char*)d_ws;
    unsigned short* qkv = (unsigned short*)(ws + OFF_QKV);
    float* attn         = (float*)(ws + OFF_ATTN);
    float* ssq          = (float*)(ws + OFF_SSQ);
    unsigned short* M   = (unsigned short*)(ws + OFF_M);

    zero_kernel<<<(N_ZERO + 255) / 256, 256, 0, stream>>>(attn, N_ZERO);
    conv_qkv<<<dim3(H / TS, Cc, B), 256, 0, stream>>>(x, w_qkv, b_qkv, qkv, ssq);
    qk_mfma<<<dim3(NSEG / 4, NH, B), 256, 0, stream>>>(qkv, attn);
    softmax_attn<<<B * NH, 64, 0, stream>>>(attn, ssq, temp);
    make_m<<<dim3(NH, B), 256, 0, stream>>>(attn, w_out, M);
    out_gemm<<<dim3(HW / BN, B), 256, 0, stream>>>(M, qkv, b_out, out);
}